// Round 1
// baseline (1053.345 us; speedup 1.0000x reference)
//
#include <hip/hip_runtime.h>

#define N_NODES 50000
#define N_EDGES 1600000
#define N_GRAPHS 64
#define D_IN 128
#define D_H 512
#define D_OUT 16

// ---------------------------------------------------------------- CSR build

__global__ __launch_bounds__(256) void count_deg(const int* __restrict__ row,
                                                 int* __restrict__ deg, int n) {
    int i = blockIdx.x * 256 + threadIdx.x;
    if (i < n) atomicAdd(&deg[row[i]], 1);
}

__global__ __launch_bounds__(256) void hist_batch(const int* __restrict__ batch,
                                                  int* __restrict__ gcnt, int n) {
    int i = blockIdx.x * 256 + threadIdx.x;
    if (i < n) atomicAdd(&gcnt[batch[i]], 1);
}

// single-block exclusive scan of deg -> rowptr; also invdeg = 1/(deg+1) (self loop)
__global__ __launch_bounds__(1024) void scan_deg(const int* __restrict__ deg,
                                                 int* __restrict__ rowptr,
                                                 float* __restrict__ invdeg, int n) {
    __shared__ int partial[1024];
    int tid = threadIdx.x;
    int chunk = (n + 1023) / 1024;
    int start = tid * chunk;
    int end = start + chunk; if (end > n) end = n;
    int s = 0;
    for (int i = start; i < end; ++i) s += deg[i];
    partial[tid] = s;
    __syncthreads();
    for (int off = 1; off < 1024; off <<= 1) {
        int v = (tid >= off) ? partial[tid - off] : 0;
        __syncthreads();
        partial[tid] += v;
        __syncthreads();
    }
    int run = (tid == 0) ? 0 : partial[tid - 1];
    for (int i = start; i < end; ++i) {
        rowptr[i] = run;
        int d = deg[i];
        invdeg[i] = 1.0f / (float)(d + 1);   // +1: self loop; always >= 1, no clip needed
        run += d;
    }
    if (tid == 1023) rowptr[n] = partial[1023];
}

__global__ __launch_bounds__(256) void scatter_edges(const int* __restrict__ row,
                                                     const int* __restrict__ col,
                                                     const int* __restrict__ rowptr,
                                                     int* __restrict__ cursor,
                                                     int* __restrict__ csr_col, int n) {
    int i = blockIdx.x * 256 + threadIdx.x;
    if (i < n) {
        int r = row[i];
        int pos = rowptr[r] + atomicAdd(&cursor[r], 1);
        csr_col[pos] = col[i];
    }
}

// ---------------------------------------------------------------- propagation
// out[r] = (x[r] + sum_{r->c} x[c]) * invdeg[r]
// one block (128 threads = feature dim) per row; gathers are 512B coalesced.

__global__ __launch_bounds__(128) void propagate(const float* __restrict__ xin,
                                                 float* __restrict__ xout,
                                                 const int* __restrict__ rowptr,
                                                 const int* __restrict__ csr_col,
                                                 const float* __restrict__ invdeg) {
    int r = blockIdx.x;
    int tid = threadIdx.x;
    int beg = rowptr[r], end = rowptr[r + 1];
    float acc = xin[(size_t)r * D_IN + tid];       // self loop
    __shared__ int cols[128];
    for (int cs = beg; cs < end; cs += 128) {
        int nn = end - cs; if (nn > 128) nn = 128;
        if (tid < nn) cols[tid] = csr_col[cs + tid];
        __syncthreads();
        int j = 0;
        for (; j + 4 <= nn; j += 4) {              // 4 independent loads in flight
            float a0 = xin[(size_t)cols[j + 0] * D_IN + tid];
            float a1 = xin[(size_t)cols[j + 1] * D_IN + tid];
            float a2 = xin[(size_t)cols[j + 2] * D_IN + tid];
            float a3 = xin[(size_t)cols[j + 3] * D_IN + tid];
            acc += a0 + a1 + a2 + a3;
        }
        for (; j < nn; ++j)
            acc += xin[(size_t)cols[j] * D_IN + tid];
        __syncthreads();
    }
    xout[(size_t)r * D_IN + tid] = acc * invdeg[r];
}

// ---------------------------------------------------------------- fused GEMM(128->512) + bias + ReLU + segmented graph-sum
// block: 256 threads, 32 nodes; thread t owns out-features {2t, 2t+1} for all 32 nodes.

__global__ __launch_bounds__(256) void gemm_relu_pool(const float* __restrict__ h,
                                                      const float* __restrict__ w1,
                                                      const float* __restrict__ b1,
                                                      const int* __restrict__ batch,
                                                      float* __restrict__ gsum, int nnodes) {
    __shared__ float hs[32][D_IN];                 // 16 KB
    int tid = threadIdx.x;
    int n0 = blockIdx.x * 32;
    int nn = nnodes - n0; if (nn > 32) nn = 32;

    for (int i = tid; i < nn * 32; i += 256) {     // 32 float4 per node row
        int n = i >> 5, kq = i & 31;
        ((float4*)hs)[n * 32 + kq] = ((const float4*)(h + (size_t)(n0 + n) * D_IN))[kq];
    }
    __syncthreads();

    int of0 = tid * 2;
    float acc0[32], acc1[32];
#pragma unroll
    for (int n = 0; n < 32; ++n) { acc0[n] = 0.f; acc1[n] = 0.f; }

    for (int k = 0; k < D_IN; k += 4) {
        float2 wv[4];
#pragma unroll
        for (int kk = 0; kk < 4; ++kk)
            wv[kk] = *(const float2*)(w1 + (size_t)(k + kk) * D_H + of0);
#pragma unroll
        for (int n = 0; n < 32; ++n) {
            float4 hv = *(const float4*)&hs[n][k];
            acc0[n] += hv.x * wv[0].x + hv.y * wv[1].x + hv.z * wv[2].x + hv.w * wv[3].x;
            acc1[n] += hv.x * wv[0].y + hv.y * wv[1].y + hv.z * wv[2].y + hv.w * wv[3].y;
        }
    }

    // bias + relu + segmented sum over sorted batch ids, then atomics per segment
    float bias0 = b1[of0], bias1 = b1[of0 + 1];
    int cur = batch[n0];
    float s0 = 0.f, s1 = 0.f;
    for (int n = 0; n < nn; ++n) {
        int g = batch[n0 + n];
        if (g != cur) {
            atomicAdd(&gsum[cur * D_H + of0], s0);
            atomicAdd(&gsum[cur * D_H + of0 + 1], s1);
            s0 = 0.f; s1 = 0.f; cur = g;
        }
        float v0 = acc0[n] + bias0; s0 += v0 > 0.f ? v0 : 0.f;
        float v1 = acc1[n] + bias1; s1 += v1 > 0.f ? v1 : 0.f;
    }
    atomicAdd(&gsum[cur * D_H + of0], s0);
    atomicAdd(&gsum[cur * D_H + of0 + 1], s1);
}

// ---------------------------------------------------------------- final: mean + (512x512) + (512x16), one block per graph

__global__ __launch_bounds__(256) void final_mlp(const float* __restrict__ gsum,
                                                 const int* __restrict__ gcnt,
                                                 const float* __restrict__ w2,
                                                 const float* __restrict__ b2,
                                                 const float* __restrict__ wc,
                                                 const float* __restrict__ bc,
                                                 float* __restrict__ out) {
    int g = blockIdx.x;
    int tid = threadIdx.x;
    __shared__ float p[D_H];
    __shared__ float h5s[D_H];
    int c = gcnt[g]; if (c < 1) c = 1;
    float inv = 1.0f / (float)c;
    for (int i = tid; i < D_H; i += 256) p[i] = gsum[g * D_H + i] * inv;
    __syncthreads();
    float a0 = b2[tid], a1 = b2[tid + 256];
    for (int k = 0; k < D_H; ++k) {
        float pv = p[k];
        a0 += pv * w2[(size_t)k * D_H + tid];
        a1 += pv * w2[(size_t)k * D_H + tid + 256];
    }
    h5s[tid] = a0; h5s[tid + 256] = a1;
    __syncthreads();
    if (tid < D_OUT) {
        float s = bc[tid];
        for (int k = 0; k < D_H; ++k) s += h5s[k] * wc[(size_t)k * D_OUT + tid];
        out[g * D_OUT + tid] = s;
    }
}

// ---------------------------------------------------------------- launch

extern "C" void kernel_launch(void* const* d_in, const int* in_sizes, int n_in,
                              void* d_out, int out_size, void* d_ws, size_t ws_size,
                              hipStream_t stream) {
    const float* x     = (const float*)d_in[0];
    const int*   eidx  = (const int*)d_in[1];   // [2, E]
    const int*   batch = (const int*)d_in[2];
    const float* w1    = (const float*)d_in[3];
    const float* b1    = (const float*)d_in[4];
    const float* w2    = (const float*)d_in[5];
    const float* b2    = (const float*)d_in[6];
    const float* wc    = (const float*)d_in[7];
    const float* bc    = (const float*)d_in[8];
    float* out = (float*)d_out;
    const int* row = eidx;
    const int* col = eidx + N_EDGES;

    char* p = (char*)d_ws;
    auto alloc = [&](size_t bytes) { char* q = p; p += (bytes + 255) & ~(size_t)255; return q; };
    int*   deg     = (int*)alloc((size_t)N_NODES * 4);
    int*   rowptr  = (int*)alloc((size_t)(N_NODES + 1) * 4);
    int*   cursor  = (int*)alloc((size_t)N_NODES * 4);
    int*   gcnt    = (int*)alloc((size_t)N_GRAPHS * 4);
    float* invdeg  = (float*)alloc((size_t)N_NODES * 4);
    float* gsum    = (float*)alloc((size_t)N_GRAPHS * D_H * 4);
    int*   csr_col = (int*)alloc((size_t)N_EDGES * 4);
    float* h0      = (float*)alloc((size_t)N_NODES * D_IN * 4);
    float* h1      = (float*)alloc((size_t)N_NODES * D_IN * 4);

    hipMemsetAsync(deg,    0, (size_t)N_NODES * 4, stream);
    hipMemsetAsync(cursor, 0, (size_t)N_NODES * 4, stream);
    hipMemsetAsync(gcnt,   0, (size_t)N_GRAPHS * 4, stream);
    hipMemsetAsync(gsum,   0, (size_t)N_GRAPHS * D_H * 4, stream);

    count_deg<<<(N_EDGES + 255) / 256, 256, 0, stream>>>(row, deg, N_EDGES);
    hist_batch<<<(N_NODES + 255) / 256, 256, 0, stream>>>(batch, gcnt, N_NODES);
    scan_deg<<<1, 1024, 0, stream>>>(deg, rowptr, invdeg, N_NODES);
    scatter_edges<<<(N_EDGES + 255) / 256, 256, 0, stream>>>(row, col, rowptr, cursor, csr_col, N_EDGES);

    propagate<<<N_NODES, 128, 0, stream>>>(x,  h0, rowptr, csr_col, invdeg);
    propagate<<<N_NODES, 128, 0, stream>>>(h0, h1, rowptr, csr_col, invdeg);
    propagate<<<N_NODES, 128, 0, stream>>>(h1, h0, rowptr, csr_col, invdeg);

    gemm_relu_pool<<<(N_NODES + 31) / 32, 256, 0, stream>>>(h0, w1, b1, batch, gsum, N_NODES);
    final_mlp<<<N_GRAPHS, 256, 0, stream>>>(gsum, gcnt, w2, b2, wc, bc, out);
}

// Round 2
// 845.206 us; speedup vs baseline: 1.2463x; 1.2463x over previous
//
#include <hip/hip_runtime.h>

#define N_NODES 50000
#define N_EDGES 1600000
#define N_GRAPHS 64
#define D_IN 128
#define D_H 512
#define D_OUT 16

// ---------------------------------------------------------------- CSR build

__global__ __launch_bounds__(256) void count_deg(const int* __restrict__ row,
                                                 int* __restrict__ deg, int n) {
    int i = blockIdx.x * 256 + threadIdx.x;
    if (i < n) atomicAdd(&deg[row[i]], 1);
}

// batch is SORTED: gcnt[g] = lower_bound(g+1) - lower_bound(g). 64 threads, no atomics.
__global__ __launch_bounds__(64) void graph_counts(const int* __restrict__ batch,
                                                   int* __restrict__ gcnt) {
    int g = threadIdx.x;
    int lo = 0, hi = N_NODES;
    while (lo < hi) { int mid = (lo + hi) >> 1; if (batch[mid] < g) lo = mid + 1; else hi = mid; }
    int a = lo;
    lo = 0; hi = N_NODES;
    while (lo < hi) { int mid = (lo + hi) >> 1; if (batch[mid] < g + 1) lo = mid + 1; else hi = mid; }
    gcnt[g] = lo - a;
}

// single-block exclusive scan of deg -> rowptr; also invdeg = 1/(deg+1) (self loop)
__global__ __launch_bounds__(1024) void scan_deg(const int* __restrict__ deg,
                                                 int* __restrict__ rowptr,
                                                 float* __restrict__ invdeg, int n) {
    __shared__ int partial[1024];
    int tid = threadIdx.x;
    int chunk = (n + 1023) / 1024;
    int start = tid * chunk;
    int end = start + chunk; if (end > n) end = n;
    int s = 0;
    for (int i = start; i < end; ++i) s += deg[i];
    partial[tid] = s;
    __syncthreads();
    for (int off = 1; off < 1024; off <<= 1) {
        int v = (tid >= off) ? partial[tid - off] : 0;
        __syncthreads();
        partial[tid] += v;
        __syncthreads();
    }
    int run = (tid == 0) ? 0 : partial[tid - 1];
    for (int i = start; i < end; ++i) {
        rowptr[i] = run;
        int d = deg[i];
        invdeg[i] = 1.0f / (float)(d + 1);   // +1: self loop; always >= 1, no clip needed
        run += d;
    }
    if (tid == 1023) rowptr[n] = partial[1023];
}

__global__ __launch_bounds__(256) void scatter_edges(const int* __restrict__ row,
                                                     const int* __restrict__ col,
                                                     const int* __restrict__ rowptr,
                                                     int* __restrict__ cursor,
                                                     int* __restrict__ csr_col, int n) {
    int i = blockIdx.x * 256 + threadIdx.x;
    if (i < n) {
        int r = row[i];
        int pos = rowptr[r] + atomicAdd(&cursor[r], 1);
        csr_col[pos] = col[i];
    }
}

// ---------------------------------------------------------------- propagation
// out[r] = (x[r] + sum_{r->c} x[c]) * invdeg[r]
// one block (128 threads = feature dim) per row; gathers are 512B coalesced.

__global__ __launch_bounds__(128) void propagate(const float* __restrict__ xin,
                                                 float* __restrict__ xout,
                                                 const int* __restrict__ rowptr,
                                                 const int* __restrict__ csr_col,
                                                 const float* __restrict__ invdeg) {
    int r = blockIdx.x;
    int tid = threadIdx.x;
    int beg = rowptr[r], end = rowptr[r + 1];
    float acc = xin[(size_t)r * D_IN + tid];       // self loop
    __shared__ int cols[128];
    for (int cs = beg; cs < end; cs += 128) {
        int nn = end - cs; if (nn > 128) nn = 128;
        if (tid < nn) cols[tid] = csr_col[cs + tid];
        __syncthreads();
        int j = 0;
        for (; j + 4 <= nn; j += 4) {              // 4 independent loads in flight
            float a0 = xin[(size_t)cols[j + 0] * D_IN + tid];
            float a1 = xin[(size_t)cols[j + 1] * D_IN + tid];
            float a2 = xin[(size_t)cols[j + 2] * D_IN + tid];
            float a3 = xin[(size_t)cols[j + 3] * D_IN + tid];
            acc += a0 + a1 + a2 + a3;
        }
        for (; j < nn; ++j)
            acc += xin[(size_t)cols[j] * D_IN + tid];
        __syncthreads();
    }
    xout[(size_t)r * D_IN + tid] = acc * invdeg[r];
}

// ---------------------------------------------------------------- fused GEMM(128->512) + bias + ReLU + segmented graph-sum
// block: 256 threads, 32 nodes; thread t owns out-features {2t, 2t+1} for all 32 nodes.

__global__ __launch_bounds__(256) void gemm_relu_pool(const float* __restrict__ h,
                                                      const float* __restrict__ w1,
                                                      const float* __restrict__ b1,
                                                      const int* __restrict__ batch,
                                                      float* __restrict__ gsum, int nnodes) {
    __shared__ float hs[32][D_IN];                 // 16 KB
    int tid = threadIdx.x;
    int n0 = blockIdx.x * 32;
    int nn = nnodes - n0; if (nn > 32) nn = 32;

    for (int i = tid; i < nn * 32; i += 256) {     // 32 float4 per node row
        int n = i >> 5, kq = i & 31;
        ((float4*)hs)[n * 32 + kq] = ((const float4*)(h + (size_t)(n0 + n) * D_IN))[kq];
    }
    __syncthreads();

    int of0 = tid * 2;
    float acc0[32], acc1[32];
#pragma unroll
    for (int n = 0; n < 32; ++n) { acc0[n] = 0.f; acc1[n] = 0.f; }

    for (int k = 0; k < D_IN; k += 4) {
        float2 wv[4];
#pragma unroll
        for (int kk = 0; kk < 4; ++kk)
            wv[kk] = *(const float2*)(w1 + (size_t)(k + kk) * D_H + of0);
#pragma unroll
        for (int n = 0; n < 32; ++n) {
            float4 hv = *(const float4*)&hs[n][k];
            acc0[n] += hv.x * wv[0].x + hv.y * wv[1].x + hv.z * wv[2].x + hv.w * wv[3].x;
            acc1[n] += hv.x * wv[0].y + hv.y * wv[1].y + hv.z * wv[2].y + hv.w * wv[3].y;
        }
    }

    // bias + relu + segmented sum over sorted batch ids, then atomics per segment
    float bias0 = b1[of0], bias1 = b1[of0 + 1];
    int cur = batch[n0];
    float s0 = 0.f, s1 = 0.f;
    for (int n = 0; n < nn; ++n) {
        int g = batch[n0 + n];
        if (g != cur) {
            atomicAdd(&gsum[cur * D_H + of0], s0);
            atomicAdd(&gsum[cur * D_H + of0 + 1], s1);
            s0 = 0.f; s1 = 0.f; cur = g;
        }
        float v0 = acc0[n] + bias0; s0 += v0 > 0.f ? v0 : 0.f;
        float v1 = acc1[n] + bias1; s1 += v1 > 0.f ? v1 : 0.f;
    }
    atomicAdd(&gsum[cur * D_H + of0], s0);
    atomicAdd(&gsum[cur * D_H + of0 + 1], s1);
}

// ---------------------------------------------------------------- final: mean + (512x512) + (512x16), one block per graph

__global__ __launch_bounds__(256) void final_mlp(const float* __restrict__ gsum,
                                                 const int* __restrict__ gcnt,
                                                 const float* __restrict__ w2,
                                                 const float* __restrict__ b2,
                                                 const float* __restrict__ wc,
                                                 const float* __restrict__ bc,
                                                 float* __restrict__ out) {
    int g = blockIdx.x;
    int tid = threadIdx.x;
    __shared__ float p[D_H];
    __shared__ float h5s[D_H];
    int c = gcnt[g]; if (c < 1) c = 1;
    float inv = 1.0f / (float)c;
    for (int i = tid; i < D_H; i += 256) p[i] = gsum[g * D_H + i] * inv;
    __syncthreads();
    float a0 = b2[tid], a1 = b2[tid + 256];
    for (int k = 0; k < D_H; ++k) {
        float pv = p[k];
        a0 += pv * w2[(size_t)k * D_H + tid];
        a1 += pv * w2[(size_t)k * D_H + tid + 256];
    }
    h5s[tid] = a0; h5s[tid + 256] = a1;
    __syncthreads();
    if (tid < D_OUT) {
        float s = bc[tid];
        for (int k = 0; k < D_H; ++k) s += h5s[k] * wc[(size_t)k * D_OUT + tid];
        out[g * D_OUT + tid] = s;
    }
}

// ---------------------------------------------------------------- launch

extern "C" void kernel_launch(void* const* d_in, const int* in_sizes, int n_in,
                              void* d_out, int out_size, void* d_ws, size_t ws_size,
                              hipStream_t stream) {
    const float* x     = (const float*)d_in[0];
    const int*   eidx  = (const int*)d_in[1];   // [2, E]
    const int*   batch = (const int*)d_in[2];
    const float* w1    = (const float*)d_in[3];
    const float* b1    = (const float*)d_in[4];
    const float* w2    = (const float*)d_in[5];
    const float* b2    = (const float*)d_in[6];
    const float* wc    = (const float*)d_in[7];
    const float* bc    = (const float*)d_in[8];
    float* out = (float*)d_out;
    const int* row = eidx;
    const int* col = eidx + N_EDGES;

    char* p = (char*)d_ws;
    auto alloc = [&](size_t bytes) { char* q = p; p += (bytes + 255) & ~(size_t)255; return q; };
    // zero-init region: deg, cursor, gsum contiguous -> ONE memset
    char* zbase = p;
    int*   deg     = (int*)alloc((size_t)N_NODES * 4);
    int*   cursor  = (int*)alloc((size_t)N_NODES * 4);
    float* gsum    = (float*)alloc((size_t)N_GRAPHS * D_H * 4);
    size_t zbytes = (size_t)(p - zbase);
    int*   rowptr  = (int*)alloc((size_t)(N_NODES + 1) * 4);
    int*   gcnt    = (int*)alloc((size_t)N_GRAPHS * 4);
    float* invdeg  = (float*)alloc((size_t)N_NODES * 4);
    int*   csr_col = (int*)alloc((size_t)N_EDGES * 4);
    float* h0      = (float*)alloc((size_t)N_NODES * D_IN * 4);
    float* h1      = (float*)alloc((size_t)N_NODES * D_IN * 4);

    hipMemsetAsync(zbase, 0, zbytes, stream);

    count_deg<<<(N_EDGES + 255) / 256, 256, 0, stream>>>(row, deg, N_EDGES);
    graph_counts<<<1, 64, 0, stream>>>(batch, gcnt);
    scan_deg<<<1, 1024, 0, stream>>>(deg, rowptr, invdeg, N_NODES);
    scatter_edges<<<(N_EDGES + 255) / 256, 256, 0, stream>>>(row, col, rowptr, cursor, csr_col, N_EDGES);

    propagate<<<N_NODES, 128, 0, stream>>>(x,  h0, rowptr, csr_col, invdeg);
    propagate<<<N_NODES, 128, 0, stream>>>(h0, h1, rowptr, csr_col, invdeg);
    propagate<<<N_NODES, 128, 0, stream>>>(h1, h0, rowptr, csr_col, invdeg);

    gemm_relu_pool<<<(N_NODES + 31) / 32, 256, 0, stream>>>(h0, w1, b1, batch, gsum, N_NODES);
    final_mlp<<<N_GRAPHS, 256, 0, stream>>>(gsum, gcnt, w2, b2, wc, bc, out);
}

// Round 4
// 595.475 us; speedup vs baseline: 1.7689x; 1.4194x over previous
//
#include <hip/hip_runtime.h>
#include <hip/hip_bf16.h>

#define N_NODES 50000
#define N_EDGES 1600000
#define N_GRAPHS 64
#define D_IN 128
#define D_H 512
#define D_OUT 16

typedef short bf16x8 __attribute__((ext_vector_type(8)));
typedef float f32x4 __attribute__((ext_vector_type(4)));

static __device__ __forceinline__ unsigned short f2bf(float f) {
    __hip_bfloat16 h = __float2bfloat16(f);   // RNE
    return *(unsigned short*)&h;
}

// ---------------------------------------------------------------- CSR build

__global__ __launch_bounds__(256) void count_deg(const int* __restrict__ row,
                                                 int* __restrict__ deg, int n) {
    int i = blockIdx.x * 256 + threadIdx.x;
    if (i < n) atomicAdd(&deg[row[i]], 1);
}

// batch is SORTED: gcnt[g] = lower_bound(g+1) - lower_bound(g). 64 threads, no atomics.
__global__ __launch_bounds__(64) void graph_counts(const int* __restrict__ batch,
                                                   int* __restrict__ gcnt) {
    int g = threadIdx.x;
    int lo = 0, hi = N_NODES;
    while (lo < hi) { int mid = (lo + hi) >> 1; if (batch[mid] < g) lo = mid + 1; else hi = mid; }
    int a = lo;
    lo = 0; hi = N_NODES;
    while (lo < hi) { int mid = (lo + hi) >> 1; if (batch[mid] < g + 1) lo = mid + 1; else hi = mid; }
    gcnt[g] = lo - a;
}

// single-block exclusive scan of deg -> rowptr; also invdeg = 1/(deg+1) (self loop)
__global__ __launch_bounds__(1024) void scan_deg(const int* __restrict__ deg,
                                                 int* __restrict__ rowptr,
                                                 float* __restrict__ invdeg, int n) {
    __shared__ int partial[1024];
    int tid = threadIdx.x;
    int chunk = (n + 1023) / 1024;
    int start = tid * chunk;
    int end = start + chunk; if (end > n) end = n;
    int s = 0;
    for (int i = start; i < end; ++i) s += deg[i];
    partial[tid] = s;
    __syncthreads();
    for (int off = 1; off < 1024; off <<= 1) {
        int v = (tid >= off) ? partial[tid - off] : 0;
        __syncthreads();
        partial[tid] += v;
        __syncthreads();
    }
    int run = (tid == 0) ? 0 : partial[tid - 1];
    for (int i = start; i < end; ++i) {
        rowptr[i] = run;
        int d = deg[i];
        invdeg[i] = 1.0f / (float)(d + 1);
        run += d;
    }
    if (tid == 1023) rowptr[n] = partial[1023];
}

__global__ __launch_bounds__(256) void scatter_edges(const int* __restrict__ row,
                                                     const int* __restrict__ col,
                                                     const int* __restrict__ rowptr,
                                                     int* __restrict__ cursor,
                                                     int* __restrict__ csr_col, int n) {
    int i = blockIdx.x * 256 + threadIdx.x;
    if (i < n) {
        int r = row[i];
        int pos = rowptr[r] + atomicAdd(&cursor[r], 1);
        csr_col[pos] = col[i];
    }
}

// ---------------------------------------------------------------- converts

// x f32 [N][128] -> packed bf16x2 [N][64]
__global__ __launch_bounds__(256) void convert_x(const float* __restrict__ x,
                                                 unsigned* __restrict__ xb, int npairs) {
    int i = blockIdx.x * 256 + threadIdx.x;
    if (i < npairs) {
        float2 v = ((const float2*)x)[i];
        xb[i] = (unsigned)f2bf(v.x) | ((unsigned)f2bf(v.y) << 16);
    }
}

// w1 f32 [128][512] -> bf16 pre-swizzled to MFMA B-frag order: [t(32)][s(4)][lane(64)][j(8)]
// B[k = s*32 + (lane>>4)*8 + j][n = t*16 + (lane&15)]
__global__ __launch_bounds__(256) void make_w1p(const float* __restrict__ w1,
                                                unsigned short* __restrict__ w1p) {
    int i = blockIdx.x * 256 + threadIdx.x;     // 65536 total
    int j = i & 7, lane = (i >> 3) & 63, s = (i >> 9) & 3, t = i >> 11;
    int k = s * 32 + (lane >> 4) * 8 + j;
    int n = t * 16 + (lane & 15);
    w1p[i] = f2bf(w1[(size_t)k * D_H + n]);
}

// ---------------------------------------------------------------- propagation (bf16 storage, f32 accumulate)
// out[r] = (x[r] + sum_{r->c} x[c]) * invdeg[r]; one wave per row; 256B coalesced row gathers.

__global__ __launch_bounds__(64) void propagate_bf16(const unsigned* __restrict__ xin,
                                                     unsigned* __restrict__ xout,
                                                     const int* __restrict__ rowptr,
                                                     const int* __restrict__ csr_col,
                                                     const float* __restrict__ invdeg) {
    int r = blockIdx.x;
    int tid = threadIdx.x;
    int beg = rowptr[r], end = rowptr[r + 1];
    unsigned u = xin[(size_t)r * 64 + tid];      // self loop
    float acc0 = __uint_as_float(u << 16);
    float acc1 = __uint_as_float(u & 0xffff0000u);
    __shared__ int cols[64];
    for (int cs = beg; cs < end; cs += 64) {
        int nn = end - cs; if (nn > 64) nn = 64;
        if (tid < nn) cols[tid] = csr_col[cs + tid];
        __syncthreads();
        int j = 0;
        for (; j + 4 <= nn; j += 4) {
            unsigned u0 = xin[(size_t)cols[j + 0] * 64 + tid];
            unsigned u1 = xin[(size_t)cols[j + 1] * 64 + tid];
            unsigned u2 = xin[(size_t)cols[j + 2] * 64 + tid];
            unsigned u3 = xin[(size_t)cols[j + 3] * 64 + tid];
            acc0 += __uint_as_float(u0 << 16) + __uint_as_float(u1 << 16)
                  + __uint_as_float(u2 << 16) + __uint_as_float(u3 << 16);
            acc1 += __uint_as_float(u0 & 0xffff0000u) + __uint_as_float(u1 & 0xffff0000u)
                  + __uint_as_float(u2 & 0xffff0000u) + __uint_as_float(u3 & 0xffff0000u);
        }
        for (; j < nn; ++j) {
            unsigned uu = xin[(size_t)cols[j] * 64 + tid];
            acc0 += __uint_as_float(uu << 16);
            acc1 += __uint_as_float(uu & 0xffff0000u);
        }
        __syncthreads();
    }
    float inv = invdeg[r];
    acc0 *= inv; acc1 *= inv;
    xout[(size_t)r * 64 + tid] = (unsigned)f2bf(acc0) | ((unsigned)f2bf(acc1) << 16);
}

// ---------------------------------------------------------------- MFMA GEMM (h3 @ w1) + bias + ReLU + segmented pool
// block 256 = 4 waves; tile M=64 (wave w -> rows w*16..), N=128 (8 n-tiles of 16); K=128 (4 steps of 32).
// A[m=lane&15][k=quad*8+j] direct from bf16 h3; B pre-swizzled; C: col=lane&15, row=quad*4+reg.

__global__ __launch_bounds__(256) void gemm_mfma_pool(const unsigned short* __restrict__ h3b,
                                                      const unsigned short* __restrict__ w1p,
                                                      const float* __restrict__ b1,
                                                      const int* __restrict__ batch,
                                                      float* __restrict__ gsum) {
    __shared__ float hls[64][132];   // +4 pad: conflict-free row-strided writes
    __shared__ int bls[64];
    int tid = threadIdx.x;
    int lane = tid & 63, wave = tid >> 6;
    int quad = lane >> 4, l15 = lane & 15;
    int mbase = blockIdx.x * 64;
    int nbase = blockIdx.y * 128;

    int m = mbase + wave * 16 + l15;
    int mc = m < N_NODES ? m : N_NODES - 1;          // clamp; garbage rows skipped in epilogue
    const unsigned short* arow = h3b + (size_t)mc * 128 + quad * 8;
    bf16x8 afrag[4];
#pragma unroll
    for (int s = 0; s < 4; ++s)
        afrag[s] = *(const bf16x8*)(arow + s * 32);

    f32x4 acc[8];
#pragma unroll
    for (int t = 0; t < 8; ++t) acc[t] = (f32x4){0.f, 0.f, 0.f, 0.f};

    const unsigned short* bbase = w1p + ((size_t)(blockIdx.y * 8) * 4 * 64 + lane) * 8;
#pragma unroll
    for (int t = 0; t < 8; ++t) {
#pragma unroll
        for (int s = 0; s < 4; ++s) {
            bf16x8 bfrag = *(const bf16x8*)(bbase + (size_t)(t * 4 + s) * 64 * 8);
            acc[t] = __builtin_amdgcn_mfma_f32_16x16x32_bf16(afrag[s], bfrag, acc[t], 0, 0, 0);
        }
    }

    if (tid < 64) {
        int mm = mbase + tid;
        bls[tid] = (mm < N_NODES) ? batch[mm] : 0;
    }
#pragma unroll
    for (int t = 0; t < 8; ++t)
#pragma unroll
        for (int rg = 0; rg < 4; ++rg)
            hls[wave * 16 + quad * 4 + rg][t * 16 + l15] = acc[t][rg];
    __syncthreads();

    // epilogue: bias + relu + sorted-segment pool; thread owns (col, 32-row half)
    int c = tid & 127, half = tid >> 7;
    float bias = b1[nbase + c];
    int r0 = half * 32;
    int cur = bls[r0];
    float s = 0.f;
    for (int r = r0; r < r0 + 32; ++r) {
        int mm = mbase + r;
        if (mm >= N_NODES) break;
        int g = bls[r];
        float v = hls[r][c] + bias;
        v = v > 0.f ? v : 0.f;
        if (g != cur) { atomicAdd(&gsum[cur * D_H + nbase + c], s); s = 0.f; cur = g; }
        s += v;
    }
    atomicAdd(&gsum[cur * D_H + nbase + c], s);
}

// ---------------------------------------------------------------- final: mean + (512x512) + (512x16), one block per graph

__global__ __launch_bounds__(256) void final_mlp(const float* __restrict__ gsum,
                                                 const int* __restrict__ gcnt,
                                                 const float* __restrict__ w2,
                                                 const float* __restrict__ b2,
                                                 const float* __restrict__ wc,
                                                 const float* __restrict__ bc,
                                                 float* __restrict__ out) {
    int g = blockIdx.x;
    int tid = threadIdx.x;
    __shared__ float p[D_H];
    __shared__ float h5s[D_H];
    int c = gcnt[g]; if (c < 1) c = 1;
    float inv = 1.0f / (float)c;
    for (int i = tid; i < D_H; i += 256) p[i] = gsum[g * D_H + i] * inv;
    __syncthreads();
    float a0 = b2[tid], a1 = b2[tid + 256];
    for (int k = 0; k < D_H; ++k) {
        float pv = p[k];
        a0 += pv * w2[(size_t)k * D_H + tid];
        a1 += pv * w2[(size_t)k * D_H + tid + 256];
    }
    h5s[tid] = a0; h5s[tid + 256] = a1;
    __syncthreads();
    if (tid < D_OUT) {
        float s = bc[tid];
        for (int k = 0; k < D_H; ++k) s += h5s[k] * wc[(size_t)k * D_OUT + tid];
        out[g * D_OUT + tid] = s;
    }
}

// ---------------------------------------------------------------- launch

extern "C" void kernel_launch(void* const* d_in, const int* in_sizes, int n_in,
                              void* d_out, int out_size, void* d_ws, size_t ws_size,
                              hipStream_t stream) {
    const float* x     = (const float*)d_in[0];
    const int*   eidx  = (const int*)d_in[1];   // [2, E]
    const int*   batch = (const int*)d_in[2];
    const float* w1    = (const float*)d_in[3];
    const float* b1    = (const float*)d_in[4];
    const float* w2    = (const float*)d_in[5];
    const float* b2    = (const float*)d_in[6];
    const float* wc    = (const float*)d_in[7];
    const float* bc    = (const float*)d_in[8];
    float* out = (float*)d_out;
    const int* row = eidx;
    const int* col = eidx + N_EDGES;

    char* p = (char*)d_ws;
    auto alloc = [&](size_t bytes) { char* q = p; p += (bytes + 255) & ~(size_t)255; return q; };
    // zero-init region: deg, cursor, gsum contiguous -> ONE memset
    char* zbase = p;
    int*   deg     = (int*)alloc((size_t)N_NODES * 4);
    int*   cursor  = (int*)alloc((size_t)N_NODES * 4);
    float* gsum    = (float*)alloc((size_t)N_GRAPHS * D_H * 4);
    size_t zbytes = (size_t)(p - zbase);
    int*   rowptr  = (int*)alloc((size_t)(N_NODES + 1) * 4);
    int*   gcnt    = (int*)alloc((size_t)N_GRAPHS * 4);
    float* invdeg  = (float*)alloc((size_t)N_NODES * 4);
    int*   csr_col = (int*)alloc((size_t)N_EDGES * 4);
    unsigned* xb   = (unsigned*)alloc((size_t)N_NODES * 64 * 4);   // bf16x2 packed
    unsigned* h0b  = (unsigned*)alloc((size_t)N_NODES * 64 * 4);
    unsigned* h1b  = (unsigned*)alloc((size_t)N_NODES * 64 * 4);
    unsigned short* w1p = (unsigned short*)alloc((size_t)D_IN * D_H * 2);

    (void)hipMemsetAsync(zbase, 0, zbytes, stream);

    convert_x<<<(N_NODES * 64 + 255) / 256, 256, 0, stream>>>(x, xb, N_NODES * 64);
    make_w1p<<<(D_IN * D_H) / 256, 256, 0, stream>>>(w1, w1p);

    count_deg<<<(N_EDGES + 255) / 256, 256, 0, stream>>>(row, deg, N_EDGES);
    graph_counts<<<1, 64, 0, stream>>>(batch, gcnt);
    scan_deg<<<1, 1024, 0, stream>>>(deg, rowptr, invdeg, N_NODES);
    scatter_edges<<<(N_EDGES + 255) / 256, 256, 0, stream>>>(row, col, rowptr, cursor, csr_col, N_EDGES);

    propagate_bf16<<<N_NODES, 64, 0, stream>>>(xb,  h0b, rowptr, csr_col, invdeg);
    propagate_bf16<<<N_NODES, 64, 0, stream>>>(h0b, h1b, rowptr, csr_col, invdeg);
    propagate_bf16<<<N_NODES, 64, 0, stream>>>(h1b, h0b, rowptr, csr_col, invdeg);

    dim3 ggrid((N_NODES + 63) / 64, D_H / 128);
    gemm_mfma_pool<<<ggrid, 256, 0, stream>>>((const unsigned short*)h0b, w1p, b1, batch, gsum);
    final_mlp<<<N_GRAPHS, 256, 0, stream>>>(gsum, gcnt, w2, b2, wc, bc, out);
}

// Round 5
// 480.422 us; speedup vs baseline: 2.1925x; 1.2395x over previous
//
#include <hip/hip_runtime.h>
#include <hip/hip_bf16.h>

#define N_NODES 50000
#define N_EDGES 1600000
#define N_GRAPHS 64
#define D_IN 128
#define D_H 512
#define D_OUT 16

#define SCAN_BLOCKS ((N_NODES + 255) / 256)      // 196
#define SCAT_PASSES 8
#define ROWS_PER_PASS ((N_NODES + SCAT_PASSES - 1) / SCAT_PASSES)   // 6250

typedef short bf16x8 __attribute__((ext_vector_type(8)));
typedef float f32x4 __attribute__((ext_vector_type(4)));

static __device__ __forceinline__ unsigned short f2bf(float f) {
    __hip_bfloat16 h = __float2bfloat16(f);   // RNE
    return *(unsigned short*)&h;
}

// ---------------------------------------------------------------- CSR build

__global__ __launch_bounds__(256) void count_deg(const int* __restrict__ row,
                                                 int* __restrict__ deg, int n) {
    int i = blockIdx.x * 256 + threadIdx.x;
    if (i < n) atomicAdd(&deg[row[i]], 1);
}

// batch is SORTED: gcnt[g] = lower_bound(g+1) - lower_bound(g). 64 threads, no atomics.
__global__ __launch_bounds__(64) void graph_counts(const int* __restrict__ batch,
                                                   int* __restrict__ gcnt) {
    int g = threadIdx.x;
    int lo = 0, hi = N_NODES;
    while (lo < hi) { int mid = (lo + hi) >> 1; if (batch[mid] < g) lo = mid + 1; else hi = mid; }
    int a = lo;
    lo = 0; hi = N_NODES;
    while (lo < hi) { int mid = (lo + hi) >> 1; if (batch[mid] < g + 1) lo = mid + 1; else hi = mid; }
    gcnt[g] = lo - a;
}

// ---- multi-block scan: (1) per-block sums, (2) scan sums, (3) write rowptr

__global__ __launch_bounds__(256) void scan_phase1(const int* __restrict__ deg,
                                                   int* __restrict__ psum) {
    __shared__ int sh[256];
    int tid = threadIdx.x;
    int i = blockIdx.x * 256 + tid;
    sh[tid] = (i < N_NODES) ? deg[i] : 0;
    __syncthreads();
    for (int off = 128; off > 0; off >>= 1) {
        if (tid < off) sh[tid] += sh[tid + off];
        __syncthreads();
    }
    if (tid == 0) psum[blockIdx.x] = sh[0];
}

__global__ __launch_bounds__(256) void scan_phase2(int* __restrict__ psum) {
    __shared__ int sh[256];
    int tid = threadIdx.x;
    sh[tid] = (tid < SCAN_BLOCKS) ? psum[tid] : 0;
    __syncthreads();
    for (int off = 1; off < 256; off <<= 1) {
        int v = (tid >= off) ? sh[tid - off] : 0;
        __syncthreads();
        sh[tid] += v;
        __syncthreads();
    }
    if (tid < SCAN_BLOCKS) psum[tid] = sh[tid] - ((tid < SCAN_BLOCKS) ? ((tid == 0) ? sh[0] : sh[tid] - sh[tid - 1]) : 0) * 0 - ((tid == 0) ? sh[0] : sh[tid] - sh[tid - 1]) + ((tid == 0) ? 0 : 0) + ((tid == 0) ? 0 : sh[tid - 1]) - ((tid == 0) ? 0 : sh[tid - 1]) + ((tid == 0) ? 0 : sh[tid - 1]) - ((tid == 0) ? 0 : 0) - ((tid == 0) ? 0 : sh[tid - 1]) + ((tid == 0) ? 0 : sh[tid - 1]);
    // exclusive: psum[t] = inclusive[t-1], psum[0] = 0
    if (tid < SCAN_BLOCKS) psum[tid] = (tid == 0) ? 0 : sh[tid - 1];
}

__global__ __launch_bounds__(256) void scan_phase3(const int* __restrict__ deg,
                                                   const int* __restrict__ psum,
                                                   int* __restrict__ rowptr,
                                                   float* __restrict__ invdeg) {
    __shared__ int sh[256];
    int tid = threadIdx.x;
    int i = blockIdx.x * 256 + tid;
    int v = (i < N_NODES) ? deg[i] : 0;
    sh[tid] = v;
    __syncthreads();
    for (int off = 1; off < 256; off <<= 1) {
        int t = (tid >= off) ? sh[tid - off] : 0;
        __syncthreads();
        sh[tid] += t;
        __syncthreads();
    }
    int incl = sh[tid];
    int base = psum[blockIdx.x];
    if (i < N_NODES) {
        rowptr[i] = base + incl - v;
        invdeg[i] = 1.0f / (float)(v + 1);
        if (i == N_NODES - 1) rowptr[N_NODES] = base + incl;
    }
}

// row-range-partitioned scatter: pass p writes only rows [p*RPP, (p+1)*RPP)
// -> csr_col writes confined to an ~800KB L2-resident window (full-line write-backs).
__global__ __launch_bounds__(256) void scatter_edges(const int* __restrict__ row,
                                                     const int* __restrict__ col,
                                                     const int* __restrict__ rowptr,
                                                     int* __restrict__ cursor,
                                                     int* __restrict__ csr_col) {
    int i = blockIdx.x * 256 + threadIdx.x;
    if (i >= N_EDGES) return;
    int lo = blockIdx.y * ROWS_PER_PASS;
    int r = row[i];
    if ((unsigned)(r - lo) < (unsigned)ROWS_PER_PASS) {
        int pos = rowptr[r] + atomicAdd(&cursor[r], 1);
        csr_col[pos] = col[i];
    }
}

// ---------------------------------------------------------------- converts

// x f32 [N][128] -> packed bf16x2 [N][64]
__global__ __launch_bounds__(256) void convert_x(const float* __restrict__ x,
                                                 unsigned* __restrict__ xb, int npairs) {
    int i = blockIdx.x * 256 + threadIdx.x;
    if (i < npairs) {
        float2 v = ((const float2*)x)[i];
        xb[i] = (unsigned)f2bf(v.x) | ((unsigned)f2bf(v.y) << 16);
    }
}

// w1 f32 [128][512] -> bf16 pre-swizzled to MFMA B-frag order: [t(32)][s(4)][lane(64)][j(8)]
// B[k = s*32 + (lane>>4)*8 + j][n = t*16 + (lane&15)]
__global__ __launch_bounds__(256) void make_w1p(const float* __restrict__ w1,
                                                unsigned short* __restrict__ w1p) {
    int i = blockIdx.x * 256 + threadIdx.x;     // 65536 total
    int j = i & 7, lane = (i >> 3) & 63, s = (i >> 9) & 3, t = i >> 11;
    int k = s * 32 + (lane >> 4) * 8 + j;
    int n = t * 16 + (lane & 15);
    w1p[i] = f2bf(w1[(size_t)k * D_H + n]);
}

// ---------------------------------------------------------------- propagation (bf16 storage, f32 accumulate)
// out[r] = (x[r] + sum_{r->c} x[c]) * invdeg[r]; one wave per row; 256B coalesced row gathers.

__global__ __launch_bounds__(64) void propagate_bf16(const unsigned* __restrict__ xin,
                                                     unsigned* __restrict__ xout,
                                                     const int* __restrict__ rowptr,
                                                     const int* __restrict__ csr_col,
                                                     const float* __restrict__ invdeg) {
    int r = blockIdx.x;
    int tid = threadIdx.x;
    int beg = rowptr[r], end = rowptr[r + 1];
    unsigned u = xin[(size_t)r * 64 + tid];      // self loop
    float acc0 = __uint_as_float(u << 16);
    float acc1 = __uint_as_float(u & 0xffff0000u);
    __shared__ int cols[64];
    for (int cs = beg; cs < end; cs += 64) {
        int nn = end - cs; if (nn > 64) nn = 64;
        if (tid < nn) cols[tid] = csr_col[cs + tid];
        __syncthreads();
        int j = 0;
        for (; j + 4 <= nn; j += 4) {
            unsigned u0 = xin[(size_t)cols[j + 0] * 64 + tid];
            unsigned u1 = xin[(size_t)cols[j + 1] * 64 + tid];
            unsigned u2 = xin[(size_t)cols[j + 2] * 64 + tid];
            unsigned u3 = xin[(size_t)cols[j + 3] * 64 + tid];
            acc0 += __uint_as_float(u0 << 16) + __uint_as_float(u1 << 16)
                  + __uint_as_float(u2 << 16) + __uint_as_float(u3 << 16);
            acc1 += __uint_as_float(u0 & 0xffff0000u) + __uint_as_float(u1 & 0xffff0000u)
                  + __uint_as_float(u2 & 0xffff0000u) + __uint_as_float(u3 & 0xffff0000u);
        }
        for (; j < nn; ++j) {
            unsigned uu = xin[(size_t)cols[j] * 64 + tid];
            acc0 += __uint_as_float(uu << 16);
            acc1 += __uint_as_float(uu & 0xffff0000u);
        }
        __syncthreads();
    }
    float inv = invdeg[r];
    acc0 *= inv; acc1 *= inv;
    xout[(size_t)r * 64 + tid] = (unsigned)f2bf(acc0) | ((unsigned)f2bf(acc1) << 16);
}

// ---------------------------------------------------------------- MFMA GEMM (h3 @ w1) + bias + ReLU + segmented pool
// block 256 = 4 waves; tile M=64, N=128; K=128 (4 steps of 32).
// A[m=lane&15][k=quad*8+j] direct from bf16 h3; B pre-swizzled; C: col=lane&15, row=quad*4+reg.

__global__ __launch_bounds__(256) void gemm_mfma_pool(const unsigned short* __restrict__ h3b,
                                                      const unsigned short* __restrict__ w1p,
                                                      const float* __restrict__ b1,
                                                      const int* __restrict__ batch,
                                                      float* __restrict__ gsum) {
    __shared__ float hls[64][132];   // +4 pad: conflict-free row-strided writes
    __shared__ int bls[64];
    int tid = threadIdx.x;
    int lane = tid & 63, wave = tid >> 6;
    int quad = lane >> 4, l15 = lane & 15;
    int mbase = blockIdx.x * 64;
    int nbase = blockIdx.y * 128;

    int m = mbase + wave * 16 + l15;
    int mc = m < N_NODES ? m : N_NODES - 1;          // clamp; garbage rows skipped in epilogue
    const unsigned short* arow = h3b + (size_t)mc * 128 + quad * 8;
    bf16x8 afrag[4];
#pragma unroll
    for (int s = 0; s < 4; ++s)
        afrag[s] = *(const bf16x8*)(arow + s * 32);

    f32x4 acc[8];
#pragma unroll
    for (int t = 0; t < 8; ++t) acc[t] = (f32x4){0.f, 0.f, 0.f, 0.f};

    const unsigned short* bbase = w1p + ((size_t)(blockIdx.y * 8) * 4 * 64 + lane) * 8;
#pragma unroll
    for (int t = 0; t < 8; ++t) {
#pragma unroll
        for (int s = 0; s < 4; ++s) {
            bf16x8 bfrag = *(const bf16x8*)(bbase + (size_t)(t * 4 + s) * 64 * 8);
            acc[t] = __builtin_amdgcn_mfma_f32_16x16x32_bf16(afrag[s], bfrag, acc[t], 0, 0, 0);
        }
    }

    if (tid < 64) {
        int mm = mbase + tid;
        bls[tid] = (mm < N_NODES) ? batch[mm] : 0;
    }
#pragma unroll
    for (int t = 0; t < 8; ++t)
#pragma unroll
        for (int rg = 0; rg < 4; ++rg)
            hls[wave * 16 + quad * 4 + rg][t * 16 + l15] = acc[t][rg];
    __syncthreads();

    // epilogue: bias + relu + sorted-segment pool; thread owns (col, 32-row half)
    int c = tid & 127, half = tid >> 7;
    float bias = b1[nbase + c];
    int r0 = half * 32;
    int cur = bls[r0];
    float s = 0.f;
    for (int r = r0; r < r0 + 32; ++r) {
        int mm = mbase + r;
        if (mm >= N_NODES) break;
        int g = bls[r];
        float v = hls[r][c] + bias;
        v = v > 0.f ? v : 0.f;
        if (g != cur) { atomicAdd(&gsum[cur * D_H + nbase + c], s); s = 0.f; cur = g; }
        s += v;
    }
    atomicAdd(&gsum[cur * D_H + nbase + c], s);
}

// ---------------------------------------------------------------- final: mean + (512x512) + (512x16), one block per graph

__global__ __launch_bounds__(256) void final_mlp(const float* __restrict__ gsum,
                                                 const int* __restrict__ gcnt,
                                                 const float* __restrict__ w2,
                                                 const float* __restrict__ b2,
                                                 const float* __restrict__ wc,
                                                 const float* __restrict__ bc,
                                                 float* __restrict__ out) {
    int g = blockIdx.x;
    int tid = threadIdx.x;
    __shared__ float p[D_H];
    __shared__ float h5s[D_H];
    int c = gcnt[g]; if (c < 1) c = 1;
    float inv = 1.0f / (float)c;
    for (int i = tid; i < D_H; i += 256) p[i] = gsum[g * D_H + i] * inv;
    __syncthreads();
    float a0 = b2[tid], a1 = b2[tid + 256];
    for (int k = 0; k < D_H; ++k) {
        float pv = p[k];
        a0 += pv * w2[(size_t)k * D_H + tid];
        a1 += pv * w2[(size_t)k * D_H + tid + 256];
    }
    h5s[tid] = a0; h5s[tid + 256] = a1;
    __syncthreads();
    if (tid < D_OUT) {
        float s = bc[tid];
        for (int k = 0; k < D_H; ++k) s += h5s[k] * wc[(size_t)k * D_OUT + tid];
        out[g * D_OUT + tid] = s;
    }
}

// ---------------------------------------------------------------- launch

extern "C" void kernel_launch(void* const* d_in, const int* in_sizes, int n_in,
                              void* d_out, int out_size, void* d_ws, size_t ws_size,
                              hipStream_t stream) {
    const float* x     = (const float*)d_in[0];
    const int*   eidx  = (const int*)d_in[1];   // [2, E]
    const int*   batch = (const int*)d_in[2];
    const float* w1    = (const float*)d_in[3];
    const float* b1    = (const float*)d_in[4];
    const float* w2    = (const float*)d_in[5];
    const float* b2    = (const float*)d_in[6];
    const float* wc    = (const float*)d_in[7];
    const float* bc    = (const float*)d_in[8];
    float* out = (float*)d_out;
    const int* row = eidx;
    const int* col = eidx + N_EDGES;

    char* p = (char*)d_ws;
    auto alloc = [&](size_t bytes) { char* q = p; p += (bytes + 255) & ~(size_t)255; return q; };
    // zero-init region: deg, cursor, gsum contiguous -> ONE memset
    char* zbase = p;
    int*   deg     = (int*)alloc((size_t)N_NODES * 4);
    int*   cursor  = (int*)alloc((size_t)N_NODES * 4);
    float* gsum    = (float*)alloc((size_t)N_GRAPHS * D_H * 4);
    size_t zbytes = (size_t)(p - zbase);
    int*   rowptr  = (int*)alloc((size_t)(N_NODES + 1) * 4);
    int*   psum    = (int*)alloc((size_t)SCAN_BLOCKS * 4);
    int*   gcnt    = (int*)alloc((size_t)N_GRAPHS * 4);
    float* invdeg  = (float*)alloc((size_t)N_NODES * 4);
    int*   csr_col = (int*)alloc((size_t)N_EDGES * 4);
    unsigned* xb   = (unsigned*)alloc((size_t)N_NODES * 64 * 4);   // bf16x2 packed
    unsigned* h0b  = (unsigned*)alloc((size_t)N_NODES * 64 * 4);
    unsigned* h1b  = (unsigned*)alloc((size_t)N_NODES * 64 * 4);
    unsigned short* w1p = (unsigned short*)alloc((size_t)D_IN * D_H * 2);

    (void)hipMemsetAsync(zbase, 0, zbytes, stream);

    convert_x<<<(N_NODES * 64 + 255) / 256, 256, 0, stream>>>(x, xb, N_NODES * 64);
    make_w1p<<<(D_IN * D_H) / 256, 256, 0, stream>>>(w1, w1p);

    count_deg<<<(N_EDGES + 255) / 256, 256, 0, stream>>>(row, deg, N_EDGES);
    graph_counts<<<1, 64, 0, stream>>>(batch, gcnt);

    scan_phase1<<<SCAN_BLOCKS, 256, 0, stream>>>(deg, psum);
    scan_phase2<<<1, 256, 0, stream>>>(psum);
    scan_phase3<<<SCAN_BLOCKS, 256, 0, stream>>>(deg, psum, rowptr, invdeg);

    dim3 sgrid((N_EDGES + 255) / 256, SCAT_PASSES);
    scatter_edges<<<sgrid, 256, 0, stream>>>(row, col, rowptr, cursor, csr_col);

    propagate_bf16<<<N_NODES, 64, 0, stream>>>(xb,  h0b, rowptr, csr_col, invdeg);
    propagate_bf16<<<N_NODES, 64, 0, stream>>>(h0b, h1b, rowptr, csr_col, invdeg);
    propagate_bf16<<<N_NODES, 64, 0, stream>>>(h1b, h0b, rowptr, csr_col, invdeg);

    dim3 ggrid((N_NODES + 63) / 64, D_H / 128);
    gemm_mfma_pool<<<ggrid, 256, 0, stream>>>((const unsigned short*)h0b, w1p, b1, batch, gsum);
    final_mlp<<<N_GRAPHS, 256, 0, stream>>>(gsum, gcnt, w2, b2, wc, bc, out);
}